// Round 1
// 767.654 us; speedup vs baseline: 1.1180x; 1.1180x over previous
//
#include <hip/hip_runtime.h>
#include <stdint.h>

#define DIM     1280
#define NHEADS  16
#define HD      80
#define NV      16
#define MAXP    1024
#define MTOT    (NV*MAXP)   // 16384

typedef __bf16 bf16;
using bf16x8 = __attribute__((ext_vector_type(8))) __bf16;
using bf16x4 = __attribute__((ext_vector_type(4))) __bf16;
using f32x4  = __attribute__((ext_vector_type(4))) float;

#define GLOAD_LDS16(g, l)                                                     \
    __builtin_amdgcn_global_load_lds(                                         \
        (const __attribute__((address_space(1))) void*)(g),                   \
        (__attribute__((address_space(3))) void*)(l), 16, 0, 0)

// ---------------------------------------------------------------------------
// fp32 -> bf16 bulk convert (vectorized, n must be a multiple of 4)
// ---------------------------------------------------------------------------
__global__ __launch_bounds__(256)
void cvt_bf16(const float* __restrict__ src, bf16* __restrict__ dst, int n4)
{
    const int i = blockIdx.x * 256 + threadIdx.x;
    if (i < n4) {
        const float4 f = ((const float4*)src)[i];
        bf16x4 r;
        r[0] = (bf16)f.x; r[1] = (bf16)f.y; r[2] = (bf16)f.z; r[3] = (bf16)f.w;
        ((bf16x4*)dst)[i] = r;
    }
}

// ---------------------------------------------------------------------------
// m97-structure NT GEMM with XOR-swizzled LDS: C = A * B^T + bias.
// (unchanged this round)
// ---------------------------------------------------------------------------
template<bool IS_QKV>
__global__ __launch_bounds__(256)
void gemm_nt_big(const bf16* __restrict__ A, const bf16* __restrict__ B,
                 const float* __restrict__ bias,
                 bf16* __restrict__ out0, bf16* __restrict__ out1,
                 bf16* __restrict__ out2, float* __restrict__ outf)
{
    const int K = DIM;
    __shared__ __align__(16) bf16 As[128*64];
    __shared__ __align__(16) bf16 Bs[128*64];

    const int tid  = threadIdx.x;
    const int lane = tid & 63, wave = tid >> 6;
    const int quad = lane >> 4, c16 = lane & 15;
    const int wm = wave & 1, wn = wave >> 1;
    const int mb = blockIdx.y, nb = blockIdx.x;

    const int sr   = lane >> 3;
    const int slot = lane & 7;
    const int sc   = (slot ^ sr) * 8;
    const long a_row0 = (long)mb * 128;
    const long b_row0 = (long)nb * 128;

    const bf16* ga[4];
    const bf16* gb[4];
    #pragma unroll
    for (int c = 0; c < 4; ++c) {
        const int seg = c*4 + wave;
        const int row = seg*8 + sr;
        ga[c] = A + (a_row0 + row)*K + sc;
        gb[c] = B + (b_row0 + row)*K + sc;
    }

    f32x4 acc[4][4] = {};
    const int xr = c16 & 7;

    for (int kt = 0; kt < K/64; ++kt) {
        const int k0 = kt * 64;
        __syncthreads();
        #pragma unroll
        for (int c = 0; c < 4; ++c) {
            const int seg = c*4 + wave;
            GLOAD_LDS16(ga[c] + k0, As + seg*512);
            GLOAD_LDS16(gb[c] + k0, Bs + seg*512);
        }
        __syncthreads();
        #pragma unroll
        for (int kk = 0; kk < 2; ++kk) {
            const int j  = kk*4 + quad;
            const int ko = ((j ^ xr) * 8);
            bf16x8 af[4], bfr[4];
            #pragma unroll
            for (int mt = 0; mt < 4; ++mt)
                af[mt] = *(const bf16x8*)(As + (wm*64 + mt*16 + c16)*64 + ko);
            #pragma unroll
            for (int nt = 0; nt < 4; ++nt)
                bfr[nt] = *(const bf16x8*)(Bs + (wn*64 + nt*16 + c16)*64 + ko);
            #pragma unroll
            for (int mt = 0; mt < 4; ++mt)
                #pragma unroll
                for (int nt = 0; nt < 4; ++nt)
                    acc[mt][nt] = __builtin_amdgcn_mfma_f32_16x16x32_bf16(
                        af[mt], bfr[nt], acc[mt][nt], 0, 0, 0);
        }
    }

    #pragma unroll
    for (int nt = 0; nt < 4; ++nt) {
        const int col = nb*128 + wn*64 + nt*16 + c16;
        const float bv = bias[col];
        if constexpr (IS_QKV) {
            const int which = col / DIM;
            const int rr = col - which*DIM;
            const int h  = rr / HD;
            const int d  = rr - h*HD;
            bf16* dst = (which == 0) ? out0 : out1;
            #pragma unroll
            for (int mt = 0; mt < 4; ++mt) {
                #pragma unroll
                for (int r = 0; r < 4; ++r) {
                    const int row = mb*128 + wm*64 + mt*16 + quad*4 + r;
                    const int n = row >> 10, p = row & 1023;
                    const bf16 bf = (bf16)(acc[mt][nt][r] + bv);
                    if (which == 2)
                        out2[((long)((n*NHEADS + h)*HD + d))*MAXP + p] = bf;   // v^T
                    else
                        dst[((long)((n*NHEADS + h)*MAXP + p))*HD + d] = bf;    // q/k
                }
            }
        } else {
            #pragma unroll
            for (int mt = 0; mt < 4; ++mt) {
                #pragma unroll
                for (int r = 0; r < 4; ++r) {
                    const int row = mb*128 + wm*64 + mt*16 + quad*4 + r;
                    outf[(long)row*DIM + col] = acc[mt][nt][r] + bv;
                }
            }
        }
    }
}

// ---------------------------------------------------------------------------
// RoPE in-place on q,k (unchanged this round)
// ---------------------------------------------------------------------------
__global__ __launch_bounds__(256)
void rope_kernel(bf16* __restrict__ qb, bf16* __restrict__ kb,
                 const float* __restrict__ rope)
{
    const int t = blockIdx.x * 256 + threadIdx.x;
    const int d = t % 40;
    const int rest = t / 40;
    const int p = rest & 1023;
    const int r2 = rest >> 10;
    const int h = r2 & 15;
    const int r3 = r2 >> 4;
    const int n = r3 & 15;
    const int a = r3 >> 4;
    bf16* arr = a ? kb : qb;
    const long base = ((long)((n*NHEADS + h)*MAXP + p))*HD;
    const float* rc = rope + ((long)(n*MAXP + p))*160;
    const float x1 = (float)arr[base + d];
    const float x2 = (float)arr[base + d + 40];
    float o1 = x1 * rc[d]      - x2 * rc[80 + d];
    float o2 = x2 * rc[40 + d] + x1 * rc[120 + d];
    const float QS = 0.11180339887498949f * 1.4426950408889634f;
    if (a == 0) { o1 *= QS; o2 *= QS; }
    arr[base + d]      = (bf16)o1;
    arr[base + d + 40] = (bf16)o2;
}

// ---------------------------------------------------------------------------
// Flash attention, swapped-operand form (softmax in exp2 domain).
// QK^T computed as mfma(K, Q) -> S^T[key][q]: each lane owns ONE q (= c16)
// and 16 key-values (4 nt-tiles x 4 regs, key = 16*nt + 4*quad + r).
//   - softmax: in-lane tree reduce + 2 shfl_xor (quad axis) for max and sum
//     (was 32 shuffles/tile/lane; now 4)
//   - P stays in registers: PV's key dimension is permuted by
//     kappa(kc,quad,j) = 32kc + 16(j>>2) + 4quad + (j&3), so the PV B-fragment
//     is exactly the lane's own 16 P values (no LDS round-trip, no barrier).
//     The matching V^T A-fragment reads columns kc*32+quad*4 (+16) as 2x b64
//     from the UNCHANGED linear Vts staging.
//   - O accumulates transposed (O^T[d][q]); one LDS transpose at the end
//     (reusing Qs) restores coalesced 16B output stores.
// LDS: 38.3 KB -> 4 blocks/CU (was 47.6 KB / 3 blocks).
// ---------------------------------------------------------------------------
__global__ __launch_bounds__(256)
void attn_kernel(const bf16* __restrict__ qb, const bf16* __restrict__ kb,
                 const bf16* __restrict__ vt, const int* __restrict__ seq_lens,
                 bf16* __restrict__ outb)
{
    __shared__ __align__(16) bf16 Qs[64*104];    // stride 104 bf16 = 208 B
    __shared__ __align__(16) bf16 Ks[64*104];
    __shared__ __align__(16) bf16 Vts[80*72];    // V^T: [d][key], stride 144 B

    const int tid  = threadIdx.x;
    const int lane = tid & 63, wave = tid >> 6;
    const int quad = lane >> 4, c16 = lane & 15;
    const int qt = blockIdx.x, h = blockIdx.y, n = blockIdx.z;
    const int seqlen = seq_lens[n];

    const long qkbase = ((long)(n*NHEADS + h)) * MAXP * HD;
    const long vbase  = ((long)(n*NHEADS + h)) * HD * MAXP;

    const float4 zero4 = make_float4(0.f, 0.f, 0.f, 0.f);

    for (int i = tid; i < 768; i += 256) {       // 64 rows x 12 chunks of 16B
        int row = i / 12, c = i % 12;
        float4 v = (c < 10)
            ? *(const float4*)(qb + qkbase + (long)(qt*64 + row)*HD + c*8)
            : zero4;
        *(float4*)(Qs + row*104 + c*8) = v;
    }
    __syncthreads();
    bf16x8 aq[3];                                // Q as B-fragment (n = own q)
    #pragma unroll
    for (int kc = 0; kc < 3; ++kc)
        aq[kc] = *(const bf16x8*)(Qs + (wave*16 + c16)*104 + kc*32 + quad*8);

    float mrow = -1e30f, lrow = 0.0f;
    f32x4 O[5] = {};                             // O^T[d = dt*16+quad*4+r][q=c16]

    union U8 { bf16x8 v; bf16x4 h[2]; };

    const int nkt = (seqlen + 63) >> 6;
    for (int kt = 0; kt < nkt; ++kt) {
        __syncthreads();
        for (int i = tid; i < 768; i += 256) {
            int row = i / 12, c = i % 12;
            float4 v = (c < 10)
                ? *(const float4*)(kb + qkbase + (long)(kt*64 + row)*HD + c*8)
                : zero4;
            *(float4*)(Ks + row*104 + c*8) = v;
        }
        for (int i = tid; i < 640; i += 256) {   // 80 d-rows x 8 chunks
            int d = i >> 3, c = i & 7;
            *(float4*)(Vts + d*72 + c*8) =
                *(const float4*)(vt + vbase + (long)d*MAXP + kt*64 + c*8);
        }
        __syncthreads();

        // S^T = K * Q^T : A = K rows (m = key), B = Q (n = q)
        f32x4 S[4] = {};
        #pragma unroll
        for (int kc = 0; kc < 3; ++kc) {
            const int ko = kc*32 + quad*8;
            #pragma unroll
            for (int nt = 0; nt < 4; ++nt) {
                bf16x8 ak = *(const bf16x8*)(Ks + (nt*16 + c16)*104 + ko);
                S[nt] = __builtin_amdgcn_mfma_f32_16x16x32_bf16(ak, aq[kc], S[nt], 0,0,0);
            }
        }
        // mask: lane's key = kt*64 + nt*16 + quad*4 + r
        #pragma unroll
        for (int nt = 0; nt < 4; ++nt) {
            const int key0 = kt*64 + nt*16 + quad*4;
            #pragma unroll
            for (int r = 0; r < 4; ++r)
                if (key0 + r >= seqlen) S[nt][r] = -1e30f;
        }

        // in-lane max tree (16 values) + 2 cross-quad shuffles
        float mx[4];
        #pragma unroll
        for (int nt = 0; nt < 4; ++nt)
            mx[nt] = fmaxf(fmaxf(S[nt][0], S[nt][1]), fmaxf(S[nt][2], S[nt][3]));
        float pmax = fmaxf(fmaxf(mx[0], mx[1]), fmaxf(mx[2], mx[3]));
        pmax = fmaxf(pmax, __shfl_xor(pmax, 16));
        pmax = fmaxf(pmax, __shfl_xor(pmax, 32));

        const float nm    = fmaxf(mrow, pmax);
        const float alpha = exp2f(mrow - nm);
        mrow = nm;

        #pragma unroll
        for (int nt = 0; nt < 4; ++nt)
            #pragma unroll
            for (int r = 0; r < 4; ++r)
                S[nt][r] = exp2f(S[nt][r] - nm);

        float sm[4];
        #pragma unroll
        for (int nt = 0; nt < 4; ++nt)
            sm[nt] = (S[nt][0] + S[nt][1]) + (S[nt][2] + S[nt][3]);
        float rs = (sm[0] + sm[1]) + (sm[2] + sm[3]);
        rs += __shfl_xor(rs, 16);
        rs += __shfl_xor(rs, 32);
        lrow = lrow * alpha + rs;

        #pragma unroll
        for (int dt = 0; dt < 5; ++dt)
            #pragma unroll
            for (int r = 0; r < 4; ++r)
                O[dt][r] *= alpha;

        // pack P (lane-local): B-frag for PV kc = [pf[2kc][0..3], pf[2kc+1][0..3]]
        bf16x8 Pk[2];
        #pragma unroll
        for (int nt = 0; nt < 4; ++nt)
            #pragma unroll
            for (int r = 0; r < 4; ++r)
                Pk[nt >> 1][(nt & 1)*4 + r] = (bf16)S[nt][r];

        // O^T += V^T * P^T with key order kappa(kc,quad,j):
        //   j=0..3 -> column kc*32 + quad*4 + j ; j=4..7 -> +16
        #pragma unroll
        for (int kc = 0; kc < 2; ++kc) {
            #pragma unroll
            for (int dt = 0; dt < 5; ++dt) {
                U8 av;
                av.h[0] = *(const bf16x4*)(Vts + (dt*16 + c16)*72 + kc*32 + quad*4);
                av.h[1] = *(const bf16x4*)(Vts + (dt*16 + c16)*72 + kc*32 + 16 + quad*4);
                O[dt] = __builtin_amdgcn_mfma_f32_16x16x32_bf16(av.v, Pk[kc], O[dt], 0,0,0);
            }
        }
    }

    // epilogue: normalize, transpose O^T -> O through Qs (dead), coalesced store
    const float inv = 1.0f / lrow;
    #pragma unroll
    for (int dt = 0; dt < 5; ++dt)
        #pragma unroll
        for (int r = 0; r < 4; ++r)
            Qs[(wave*16 + c16)*104 + dt*16 + quad*4 + r] = (bf16)(O[dt][r] * inv);
    __syncthreads();
    for (int i = tid; i < 640; i += 256) {       // 64 rows x 10 chunks of 16B
        const int row = i / 10, c = i % 10;
        const float4 v = *(const float4*)(Qs + row*104 + c*8);
        *(float4*)(outb + ((long)(n*MAXP + qt*64 + row))*DIM + h*HD + c*8) = v;
    }
}

// ---------------------------------------------------------------------------
// Buffer plan:
//   d_ws   : hidden_bf (42 MB) | wqkv_bf (9.8 MB) | wproj_bf (3.3 MB)
//   d_out  : q (42 MB bf16) | k (42 MB bf16)  — overwritten by proj fp32 at end
//   d_in[0]: vT (42 MB bf16) | attn_out (42 MB bf16) — hidden fp32 dead after cvt
// ---------------------------------------------------------------------------
extern "C" void kernel_launch(void* const* d_in, const int* in_sizes, int n_in,
                              void* d_out, int out_size, void* d_ws, size_t ws_size,
                              hipStream_t stream)
{
    const float* hidden = (const float*)d_in[0];
    const float* rope   = (const float*)d_in[1];
    const int*   seql   = (const int*)d_in[2];
    const float* wqkv   = (const float*)d_in[3];
    const float* bqkv   = (const float*)d_in[4];
    const float* wproj  = (const float*)d_in[5];
    const float* bproj  = (const float*)d_in[6];
    float* out = (float*)d_out;

    const size_t H_ELEMS  = (size_t)MTOT*DIM;          // 20,971,520
    const size_t WQ_ELEMS = (size_t)3*DIM*DIM;         //  4,915,200
    const size_t WP_ELEMS = (size_t)DIM*DIM;           //  1,638,400
    const size_t QK_ELEMS = (size_t)NV*NHEADS*MAXP*HD; // 20,971,520

    bf16* h_bf  = (bf16*)d_ws;
    bf16* wq_bf = h_bf  + H_ELEMS;
    bf16* wp_bf = wq_bf + WQ_ELEMS;

    bf16* q_b = (bf16*)d_out;
    bf16* k_b = q_b + QK_ELEMS;
    bf16* v_t = (bf16*)d_in[0];
    bf16* a_b = v_t + QK_ELEMS;

    cvt_bf16<<<(H_ELEMS/4 + 255)/256, 256, 0, stream>>>(hidden, h_bf, H_ELEMS/4);
    cvt_bf16<<<(WQ_ELEMS/4 + 255)/256, 256, 0, stream>>>(wqkv, wq_bf, WQ_ELEMS/4);
    cvt_bf16<<<(WP_ELEMS/4 + 255)/256, 256, 0, stream>>>(wproj, wp_bf, WP_ELEMS/4);

    gemm_nt_big<true><<<dim3(3*DIM/128, MTOT/128), 256, 0, stream>>>(
        h_bf, wq_bf, bqkv, q_b, k_b, v_t, nullptr);

    rope_kernel<<<(2*NV*NHEADS*MAXP*40)/256, 256, 0, stream>>>(q_b, k_b, rope);

    attn_kernel<<<dim3(MAXP/64, NHEADS, NV), 256, 0, stream>>>(
        q_b, k_b, v_t, seql, a_b);

    gemm_nt_big<false><<<dim3(DIM/128, MTOT/128), 256, 0, stream>>>(
        a_b, wp_bf, bproj, nullptr, nullptr, nullptr, out);
}

// Round 2
// 693.834 us; speedup vs baseline: 1.2369x; 1.1064x over previous
//
#include <hip/hip_runtime.h>
#include <stdint.h>

#define DIM     1280
#define NHEADS  16
#define HD      80
#define NV      16
#define MAXP    1024
#define MTOT    (NV*MAXP)   // 16384

typedef __bf16 bf16;
using bf16x8 = __attribute__((ext_vector_type(8))) __bf16;
using bf16x4 = __attribute__((ext_vector_type(4))) __bf16;
using f32x4  = __attribute__((ext_vector_type(4))) float;

#define GLOAD_LDS16(g, l)                                                     \
    __builtin_amdgcn_global_load_lds(                                         \
        (const __attribute__((address_space(1))) void*)(g),                   \
        (__attribute__((address_space(3))) void*)(l), 16, 0, 0)

// ---------------------------------------------------------------------------
// fp32 -> bf16 bulk convert (vectorized, n must be a multiple of 4)
// ---------------------------------------------------------------------------
__global__ __launch_bounds__(256)
void cvt_bf16(const float* __restrict__ src, bf16* __restrict__ dst, int n4)
{
    const int i = blockIdx.x * 256 + threadIdx.x;
    if (i < n4) {
        const float4 f = ((const float4*)src)[i];
        bf16x4 r;
        r[0] = (bf16)f.x; r[1] = (bf16)f.y; r[2] = (bf16)f.z; r[3] = (bf16)f.w;
        ((bf16x4*)dst)[i] = r;
    }
}

// ---------------------------------------------------------------------------
// m97-structure NT GEMM with XOR-swizzled LDS: C = A * B^T + bias.
// NEW: 1-D grid + XCD-chunked swizzle (T1). HW maps bid%8 -> XCD; each XCD
// owns a disjoint band of 16 mb-panels, iterated nb-group-fastest:
//   xcd = bid&7, idx = bid>>3 ; nbg = idx/(16*G); rem = idx%(16*G);
//   mb = xcd*16 + rem/G ; nb = nbg*G + rem%G
// -> A-panel filled into exactly ONE L2; B group (G panels) stays L2-hot.
// NEW: v^T epilogue staged through LDS (reuses As/Bs) for coalesced stores.
// ---------------------------------------------------------------------------
template<bool IS_QKV, int NB, int G>
__global__ __launch_bounds__(256)
void gemm_nt_big(const bf16* __restrict__ A, const bf16* __restrict__ B,
                 const float* __restrict__ bias,
                 bf16* __restrict__ out0, bf16* __restrict__ out1,
                 bf16* __restrict__ out2, float* __restrict__ outf)
{
    const int K = DIM;
    __shared__ __align__(16) bf16 SH[2*128*64];   // As | Bs ; reused as C-tile
    bf16* const As = SH;
    bf16* const Bs = SH + 128*64;

    const int tid  = threadIdx.x;
    const int lane = tid & 63, wave = tid >> 6;
    const int quad = lane >> 4, c16 = lane & 15;
    const int wm = wave & 1, wn = wave >> 1;

    // XCD-chunked block swizzle (bijective: grid = 8 * 16 * NB)
    const int bid = blockIdx.x;
    const int xcd = bid & 7;
    const int idx = bid >> 3;
    const int nbg = idx / (16*G);
    const int rem = idx % (16*G);
    const int mb  = xcd*16 + rem / G;
    const int nb  = nbg*G  + rem % G;

    const int sr   = lane >> 3;
    const int slot = lane & 7;
    const int sc   = (slot ^ sr) * 8;
    const long a_row0 = (long)mb * 128;
    const long b_row0 = (long)nb * 128;

    const bf16* ga[4];
    const bf16* gb[4];
    #pragma unroll
    for (int c = 0; c < 4; ++c) {
        const int seg = c*4 + wave;
        const int row = seg*8 + sr;
        ga[c] = A + (a_row0 + row)*K + sc;
        gb[c] = B + (b_row0 + row)*K + sc;
    }

    f32x4 acc[4][4] = {};
    const int xr = c16 & 7;

    for (int kt = 0; kt < K/64; ++kt) {
        const int k0 = kt * 64;
        __syncthreads();
        #pragma unroll
        for (int c = 0; c < 4; ++c) {
            const int seg = c*4 + wave;
            GLOAD_LDS16(ga[c] + k0, As + seg*512);
            GLOAD_LDS16(gb[c] + k0, Bs + seg*512);
        }
        __syncthreads();
        #pragma unroll
        for (int kk = 0; kk < 2; ++kk) {
            const int j  = kk*4 + quad;
            const int ko = ((j ^ xr) * 8);
            bf16x8 af[4], bfr[4];
            #pragma unroll
            for (int mt = 0; mt < 4; ++mt)
                af[mt] = *(const bf16x8*)(As + (wm*64 + mt*16 + c16)*64 + ko);
            #pragma unroll
            for (int nt = 0; nt < 4; ++nt)
                bfr[nt] = *(const bf16x8*)(Bs + (wn*64 + nt*16 + c16)*64 + ko);
            #pragma unroll
            for (int mt = 0; mt < 4; ++mt)
                #pragma unroll
                for (int nt = 0; nt < 4; ++nt)
                    acc[mt][nt] = __builtin_amdgcn_mfma_f32_16x16x32_bf16(
                        af[mt], bfr[nt], acc[mt][nt], 0, 0, 0);
        }
    }

    if constexpr (IS_QKV) {
        const int which = nb / 10;               // block-uniform (128 | 1280)
        if (which < 2) {
            // q/k: direct stores (32B-granule per 16-lane group)
            bf16* const dst = (which == 0) ? out0 : out1;
            #pragma unroll
            for (int nt = 0; nt < 4; ++nt) {
                const int col = nb*128 + wn*64 + nt*16 + c16;
                const float bv = bias[col];
                const int rr = col - which*DIM;
                const int h  = rr / HD;
                const int d  = rr - h*HD;
                #pragma unroll
                for (int mt = 0; mt < 4; ++mt) {
                    #pragma unroll
                    for (int r = 0; r < 4; ++r) {
                        const int row = mb*128 + wm*64 + mt*16 + quad*4 + r;
                        const int n = row >> 10, p = row & 1023;
                        dst[((long)((n*NHEADS + h)*MAXP + p))*HD + d] =
                            (bf16)(acc[mt][nt][r] + bv);
                    }
                }
            }
        } else {
            // v^T: stage C-tile into LDS as VT[d][p ^ ((d&15)<<3)], then
            // coalesced 16B stores along p.
            __syncthreads();                     // K-loop LDS reads done
            #pragma unroll
            for (int nt = 0; nt < 4; ++nt) {
                const int dl0 = wn*64 + nt*16 + c16;       // local d 0..127
                const float bv = bias[nb*128 + dl0];
                const int swz = (dl0 & 15) << 3;
                #pragma unroll
                for (int mt = 0; mt < 4; ++mt) {
                    #pragma unroll
                    for (int r = 0; r < 4; ++r) {
                        const int pl = wm*64 + mt*16 + quad*4 + r;
                        SH[dl0*128 + (pl ^ swz)] = (bf16)(acc[mt][nt][r] + bv);
                    }
                }
            }
            __syncthreads();
            const int n_    = mb >> 3;           // 1024/128 = 8 tiles per image
            const int pbase = (mb & 7) * 128;
            #pragma unroll
            for (int it = 0; it < 8; ++it) {
                const int c  = tid + 256*it;     // 0..2047
                const int dl = c >> 4, j = c & 15;
                const int p0 = (j ^ (dl & 15)) << 3;
                const int rr = (nb - 20)*128 + dl;
                const int hh = rr / HD;
                const int dd = rr - hh*HD;
                bf16x8 v = *(const bf16x8*)(SH + dl*128 + j*8);
                *(bf16x8*)(out2 + ((long)((n_*NHEADS + hh)*HD + dd))*MAXP
                                  + pbase + p0) = v;
            }
        }
    } else {
        #pragma unroll
        for (int nt = 0; nt < 4; ++nt) {
            const int col = nb*128 + wn*64 + nt*16 + c16;
            const float bv = bias[col];
            #pragma unroll
            for (int mt = 0; mt < 4; ++mt) {
                #pragma unroll
                for (int r = 0; r < 4; ++r) {
                    const int row = mb*128 + wm*64 + mt*16 + quad*4 + r;
                    outf[(long)row*DIM + col] = acc[mt][nt][r] + bv;
                }
            }
        }
    }
}

// ---------------------------------------------------------------------------
// RoPE in-place on q,k — vectorized (bf16x8 octets + float4 rope loads).
// Block = 320 threads = 64 rows x 5 d-octets. Row = (a,n,h,p), p fastest.
// q additionally scaled by log2(e)/sqrt(80) (softmax runs in exp2 domain).
// ---------------------------------------------------------------------------
__global__ __launch_bounds__(320)
void rope_kernel(bf16* __restrict__ qb, bf16* __restrict__ kb,
                 const float* __restrict__ rope)
{
    const int tid = threadIdx.x;
    const int j   = tid % 5;                  // d-octet 0..4  (d = j*8)
    const int rl  = tid / 5;                  // local row 0..63
    const long grow = (long)blockIdx.x * 64 + rl;   // 0..524287
    const int p = (int)(grow & 1023);
    const int h = (int)((grow >> 10) & 15);
    const int n = (int)((grow >> 14) & 15);
    const int a = (int)(grow >> 18);          // 0 = q, 1 = k
    bf16* const arr = a ? kb : qb;
    const long base = ((long)((n*NHEADS + h)*MAXP + p))*HD;
    const float* rc = rope + ((long)(n*MAXP + p))*160;
    const int d = j*8;

    bf16x8 x1v = *(const bf16x8*)(arr + base + d);
    bf16x8 x2v = *(const bf16x8*)(arr + base + 40 + d);

    float c1[8], s1[8], c2[8], s2[8];
    *(float4*)(c1)   = *(const float4*)(rc + d);
    *(float4*)(c1+4) = *(const float4*)(rc + d + 4);
    *(float4*)(s1)   = *(const float4*)(rc + 80 + d);
    *(float4*)(s1+4) = *(const float4*)(rc + 80 + d + 4);
    *(float4*)(c2)   = *(const float4*)(rc + 40 + d);
    *(float4*)(c2+4) = *(const float4*)(rc + 40 + d + 4);
    *(float4*)(s2)   = *(const float4*)(rc + 120 + d);
    *(float4*)(s2+4) = *(const float4*)(rc + 120 + d + 4);

    const float QS = 0.11180339887498949f * 1.4426950408889634f;
    bf16x8 r1, r2;
    #pragma unroll
    for (int i = 0; i < 8; ++i) {
        const float x1 = (float)x1v[i];
        const float x2 = (float)x2v[i];
        float o1 = x1 * c1[i] - x2 * s1[i];
        float o2 = x2 * c2[i] + x1 * s2[i];
        if (a == 0) { o1 *= QS; o2 *= QS; }
        r1[i] = (bf16)o1;
        r2[i] = (bf16)o2;
    }
    *(bf16x8*)(arr + base + d)      = r1;
    *(bf16x8*)(arr + base + 40 + d) = r2;
}

// ---------------------------------------------------------------------------
// Flash attention, swapped-operand form (unchanged this round).
// ---------------------------------------------------------------------------
__global__ __launch_bounds__(256)
void attn_kernel(const bf16* __restrict__ qb, const bf16* __restrict__ kb,
                 const bf16* __restrict__ vt, const int* __restrict__ seq_lens,
                 bf16* __restrict__ outb)
{
    __shared__ __align__(16) bf16 Qs[64*104];    // stride 104 bf16 = 208 B
    __shared__ __align__(16) bf16 Ks[64*104];
    __shared__ __align__(16) bf16 Vts[80*72];    // V^T: [d][key], stride 144 B

    const int tid  = threadIdx.x;
    const int lane = tid & 63, wave = tid >> 6;
    const int quad = lane >> 4, c16 = lane & 15;
    const int qt = blockIdx.x, h = blockIdx.y, n = blockIdx.z;
    const int seqlen = seq_lens[n];

    const long qkbase = ((long)(n*NHEADS + h)) * MAXP * HD;
    const long vbase  = ((long)(n*NHEADS + h)) * HD * MAXP;

    const float4 zero4 = make_float4(0.f, 0.f, 0.f, 0.f);

    for (int i = tid; i < 768; i += 256) {       // 64 rows x 12 chunks of 16B
        int row = i / 12, c = i % 12;
        float4 v = (c < 10)
            ? *(const float4*)(qb + qkbase + (long)(qt*64 + row)*HD + c*8)
            : zero4;
        *(float4*)(Qs + row*104 + c*8) = v;
    }
    __syncthreads();
    bf16x8 aq[3];                                // Q as B-fragment (n = own q)
    #pragma unroll
    for (int kc = 0; kc < 3; ++kc)
        aq[kc] = *(const bf16x8*)(Qs + (wave*16 + c16)*104 + kc*32 + quad*8);

    float mrow = -1e30f, lrow = 0.0f;
    f32x4 O[5] = {};                             // O^T[d = dt*16+quad*4+r][q=c16]

    union U8 { bf16x8 v; bf16x4 h[2]; };

    const int nkt = (seqlen + 63) >> 6;
    for (int kt = 0; kt < nkt; ++kt) {
        __syncthreads();
        for (int i = tid; i < 768; i += 256) {
            int row = i / 12, c = i % 12;
            float4 v = (c < 10)
                ? *(const float4*)(kb + qkbase + (long)(kt*64 + row)*HD + c*8)
                : zero4;
            *(float4*)(Ks + row*104 + c*8) = v;
        }
        for (int i = tid; i < 640; i += 256) {   // 80 d-rows x 8 chunks
            int d = i >> 3, c = i & 7;
            *(float4*)(Vts + d*72 + c*8) =
                *(const float4*)(vt + vbase + (long)d*MAXP + kt*64 + c*8);
        }
        __syncthreads();

        // S^T = K * Q^T : A = K rows (m = key), B = Q (n = q)
        f32x4 S[4] = {};
        #pragma unroll
        for (int kc = 0; kc < 3; ++kc) {
            const int ko = kc*32 + quad*8;
            #pragma unroll
            for (int nt = 0; nt < 4; ++nt) {
                bf16x8 ak = *(const bf16x8*)(Ks + (nt*16 + c16)*104 + ko);
                S[nt] = __builtin_amdgcn_mfma_f32_16x16x32_bf16(ak, aq[kc], S[nt], 0,0,0);
            }
        }
        // mask: lane's key = kt*64 + nt*16 + quad*4 + r
        #pragma unroll
        for (int nt = 0; nt < 4; ++nt) {
            const int key0 = kt*64 + nt*16 + quad*4;
            #pragma unroll
            for (int r = 0; r < 4; ++r)
                if (key0 + r >= seqlen) S[nt][r] = -1e30f;
        }

        // in-lane max tree (16 values) + 2 cross-quad shuffles
        float mx[4];
        #pragma unroll
        for (int nt = 0; nt < 4; ++nt)
            mx[nt] = fmaxf(fmaxf(S[nt][0], S[nt][1]), fmaxf(S[nt][2], S[nt][3]));
        float pmax = fmaxf(fmaxf(mx[0], mx[1]), fmaxf(mx[2], mx[3]));
        pmax = fmaxf(pmax, __shfl_xor(pmax, 16));
        pmax = fmaxf(pmax, __shfl_xor(pmax, 32));

        const float nm    = fmaxf(mrow, pmax);
        const float alpha = exp2f(mrow - nm);
        mrow = nm;

        #pragma unroll
        for (int nt = 0; nt < 4; ++nt)
            #pragma unroll
            for (int r = 0; r < 4; ++r)
                S[nt][r] = exp2f(S[nt][r] - nm);

        float sm[4];
        #pragma unroll
        for (int nt = 0; nt < 4; ++nt)
            sm[nt] = (S[nt][0] + S[nt][1]) + (S[nt][2] + S[nt][3]);
        float rs = (sm[0] + sm[1]) + (sm[2] + sm[3]);
        rs += __shfl_xor(rs, 16);
        rs += __shfl_xor(rs, 32);
        lrow = lrow * alpha + rs;

        #pragma unroll
        for (int dt = 0; dt < 5; ++dt)
            #pragma unroll
            for (int r = 0; r < 4; ++r)
                O[dt][r] *= alpha;

        // pack P (lane-local): B-frag for PV kc = [pf[2kc][0..3], pf[2kc+1][0..3]]
        bf16x8 Pk[2];
        #pragma unroll
        for (int nt = 0; nt < 4; ++nt)
            #pragma unroll
            for (int r = 0; r < 4; ++r)
                Pk[nt >> 1][(nt & 1)*4 + r] = (bf16)S[nt][r];

        // O^T += V^T * P^T with key order kappa(kc,quad,j)
        #pragma unroll
        for (int kc = 0; kc < 2; ++kc) {
            #pragma unroll
            for (int dt = 0; dt < 5; ++dt) {
                U8 av;
                av.h[0] = *(const bf16x4*)(Vts + (dt*16 + c16)*72 + kc*32 + quad*4);
                av.h[1] = *(const bf16x4*)(Vts + (dt*16 + c16)*72 + kc*32 + 16 + quad*4);
                O[dt] = __builtin_amdgcn_mfma_f32_16x16x32_bf16(av.v, Pk[kc], O[dt], 0,0,0);
            }
        }
    }

    // epilogue: normalize, transpose O^T -> O through Qs (dead), coalesced store
    const float inv = 1.0f / lrow;
    #pragma unroll
    for (int dt = 0; dt < 5; ++dt)
        #pragma unroll
        for (int r = 0; r < 4; ++r)
            Qs[(wave*16 + c16)*104 + dt*16 + quad*4 + r] = (bf16)(O[dt][r] * inv);
    __syncthreads();
    for (int i = tid; i < 640; i += 256) {       // 64 rows x 10 chunks of 16B
        const int row = i / 10, c = i % 10;
        const float4 v = *(const float4*)(Qs + row*104 + c*8);
        *(float4*)(outb + ((long)(n*MAXP + qt*64 + row))*DIM + h*HD + c*8) = v;
    }
}

// ---------------------------------------------------------------------------
// Buffer plan:
//   d_ws   : hidden_bf (42 MB) | wqkv_bf (9.8 MB) | wproj_bf (3.3 MB)
//   d_out  : q (42 MB bf16) | k (42 MB bf16)  — overwritten by proj fp32 at end
//   d_in[0]: vT (42 MB bf16) | attn_out (42 MB bf16) — hidden fp32 dead after cvt
// ---------------------------------------------------------------------------
extern "C" void kernel_launch(void* const* d_in, const int* in_sizes, int n_in,
                              void* d_out, int out_size, void* d_ws, size_t ws_size,
                              hipStream_t stream)
{
    const float* hidden = (const float*)d_in[0];
    const float* rope   = (const float*)d_in[1];
    const int*   seql   = (const int*)d_in[2];
    const float* wqkv   = (const float*)d_in[3];
    const float* bqkv   = (const float*)d_in[4];
    const float* wproj  = (const float*)d_in[5];
    const float* bproj  = (const float*)d_in[6];
    float* out = (float*)d_out;

    const size_t H_ELEMS  = (size_t)MTOT*DIM;          // 20,971,520
    const size_t WQ_ELEMS = (size_t)3*DIM*DIM;         //  4,915,200
    const size_t WP_ELEMS = (size_t)DIM*DIM;           //  1,638,400
    const size_t QK_ELEMS = (size_t)NV*NHEADS*MAXP*HD; // 20,971,520

    bf16* h_bf  = (bf16*)d_ws;
    bf16* wq_bf = h_bf  + H_ELEMS;
    bf16* wp_bf = wq_bf + WQ_ELEMS;

    bf16* q_b = (bf16*)d_out;
    bf16* k_b = q_b + QK_ELEMS;
    bf16* v_t = (bf16*)d_in[0];
    bf16* a_b = v_t + QK_ELEMS;

    cvt_bf16<<<(H_ELEMS/4 + 255)/256, 256, 0, stream>>>(hidden, h_bf, H_ELEMS/4);
    cvt_bf16<<<(WQ_ELEMS/4 + 255)/256, 256, 0, stream>>>(wqkv, wq_bf, WQ_ELEMS/4);
    cvt_bf16<<<(WP_ELEMS/4 + 255)/256, 256, 0, stream>>>(wproj, wp_bf, WP_ELEMS/4);

    // QKV: grid = 8 XCD * 16 mb * 30 nb = 3840 ; G=6 (B group 1.9 MB in L2)
    gemm_nt_big<true, 30, 6><<<3840, 256, 0, stream>>>(
        h_bf, wq_bf, bqkv, q_b, k_b, v_t, nullptr);

    // rows = 2*16*16*1024 = 524288 ; 64 rows/block, 320 threads
    rope_kernel<<<524288/64, 320, 0, stream>>>(q_b, k_b, rope);

    attn_kernel<<<dim3(MAXP/64, NHEADS, NV), 256, 0, stream>>>(
        q_b, k_b, v_t, seql, a_b);

    // proj: grid = 8 * 16 * 10 = 1280 ; G=10 (whole wproj 3.3 MB in L2)
    gemm_nt_big<false, 10, 10><<<1280, 256, 0, stream>>>(
        a_b, wp_bf, bproj, nullptr, nullptr, nullptr, out);
}